// Round 23
// baseline (1262.916 us; speedup 1.0000x reference)
//
#include <hip/hip_runtime.h>

typedef _Float16 h2_t __attribute__((ext_vector_type(2)));
typedef _Float16 h4_t __attribute__((ext_vector_type(4)));
typedef _Float16 h8_t __attribute__((ext_vector_type(8)));
typedef float    f4_t __attribute__((ext_vector_type(4)));
typedef int      v4i  __attribute__((ext_vector_type(4)));

#define B_  64
#define T_  512
#define F_  128
#define H_  512

// fast tanh: sign(x) * (1 - e) / (1 + e), e = exp(-2|x|)
static __device__ __forceinline__ float tanh_fast(float x) {
    float ax = fabsf(x);
    float e = __expf(-2.f * ax);
    float r = (1.f - e) * __frcp_rn(1.f + e);
    return copysignf(r, x);
}

// ---------------- prep kernels ----------------
__global__ void k_cast_f16(const float* __restrict__ src, _Float16* __restrict__ dst, int n) {
    int i = blockIdx.x * blockDim.x + threadIdx.x;
    if (i < n) dst[i] = (_Float16)src[i];
}

// Wz[c][k] = Wih_de[c][512+k]  (z-contribution of the decoder input weight)
__global__ void k_prep_z(const float* __restrict__ Wih_de, _Float16* __restrict__ Wz) {
    int i = blockIdx.x * blockDim.x + threadIdx.x;   // over 512*512
    int cc = i >> 9, kk = i & 511;
    Wz[i] = (_Float16)Wih_de[cc * 1024 + 512 + kk];
}

__global__ void k_prep_bias(const float* __restrict__ a, const float* __restrict__ b,
                            float* __restrict__ o) {
    int i = threadIdx.x;
    o[i] = a[i] + b[i];
}

// o[0..n) = a, o[n..2n) = b
__global__ void k_cat2(const float* __restrict__ a, const float* __restrict__ b,
                       float* __restrict__ o, int n) {
    int i = blockIdx.x * blockDim.x + threadIdx.x;
    if (i < 2 * n) o[i] = (i < n) ? a[i] : b[i - n];
}

// per-row symmetric int8 quantization of W (optionally A+B elementwise).
__global__ void k_quant(const float* __restrict__ A, int sA,
                        const float* __restrict__ Bo, int sB,
                        signed char* __restrict__ q, float* __restrict__ fac) {
    __shared__ float red[128];
    const int c = blockIdx.x, t = threadIdx.x;
    f4_t v = *(const f4_t*)(A + (size_t)c * sA + t * 4);
    if (Bo) {
        f4_t vb = *(const f4_t*)(Bo + (size_t)c * sB + t * 4);
        v = v + vb;
    }
    float m = fmaxf(fmaxf(fabsf(v[0]), fabsf(v[1])), fmaxf(fabsf(v[2]), fabsf(v[3])));
    red[t] = m;
    __syncthreads();
    for (int o = 64; o; o >>= 1) {
        if (t < o) red[t] = fmaxf(red[t], red[t + o]);
        __syncthreads();
    }
    float mx = red[0];
    float inv = mx > 0.f ? 127.f / mx : 0.f;
    unsigned r = 0;
    #pragma unroll
    for (int i = 0; i < 4; ++i) {
        int qi = (int)rintf(fminf(fmaxf(v[i] * inv, -127.f), 127.f));
        r |= ((unsigned)(unsigned char)(signed char)qi) << (8 * i);
    }
    *(unsigned*)(q + (size_t)c * 512 + t * 4) = r;
    if (t == 0) fac[c] = mx > 0.f ? mx / 127.f : 0.f;
}

// repack Wq [512][512] i8 into MFMA A-fragment order for k_rnn:
// thread tid (wave w = tid>>6, lane l = tid&63), slot s = kt*4 + rt (32 slots):
//   A-frag chunk = Wq[row m][k0..k0+15],  m = w*64 + rt*16 + (l&15),
//   k0 = kt*64 + ((l>>4)&3)*16
// (standard 16x16 A layout: lane = m + 16*kgroup).  W5[s*512 + tid] = chunk.
__global__ void k_repack(const signed char* __restrict__ Wq, uint4* __restrict__ W5) {
    int gid = blockIdx.x * blockDim.x + threadIdx.x;   // over 32*512
    int s = gid >> 9, tid2 = gid & 511;
    int kt = s >> 2, rt = s & 3;
    int w = tid2 >> 6, l = tid2 & 63;
    int m = w * 64 + rt * 16 + (l & 15);
    int k0 = kt * 64 + ((l >> 4) & 3) * 16;
    W5[gid] = *(const uint4*)(Wq + (size_t)m * 512 + k0);
}

// ---------------- GEMM: C[M,N] = A[M,K] @ Bt[N,K]^T + bias[N] ----------------
#define BM 128
#define BN 128
#define BK 32
#define LDT 40   // padded LDS row stride in f16 units

__global__ __launch_bounds__(256) void k_gemm(
    const _Float16* __restrict__ A, const _Float16* __restrict__ Bt,
    const float* __restrict__ bias,
    float* __restrict__ Cf, float* __restrict__ Cf2, _Float16* __restrict__ Ch,
    int M, int N, int nsplit, int K) {
    __shared__ _Float16 Al[BM * LDT];
    __shared__ _Float16 Bl[BN * LDT];
    const int tid = threadIdx.x;
    const int bm = blockIdx.x * BM, bn = blockIdx.y * BN;
    const int wid = tid >> 6, lane = tid & 63;
    const int wm = (wid >> 1) * 64, wn = (wid & 1) * 64;
    const int l15 = lane & 15, l4 = lane >> 4;

    f4_t acc[4][4];
    #pragma unroll
    for (int i = 0; i < 4; ++i)
        #pragma unroll
        for (int j = 0; j < 4; ++j) {
            f4_t zz = {0.f, 0.f, 0.f, 0.f};
            acc[i][j] = zz;
        }

    const int r = tid >> 1, hf = tid & 1;
    const h8_t* gA0 = (const h8_t*)(A + (size_t)(bm + r) * K);
    const h8_t* gB0 = (const h8_t*)(Bt + (size_t)(bn + r) * K);

    for (int k0 = 0; k0 < K; k0 += BK) {
        __syncthreads();
        int kf = (k0 >> 3) + hf * 2;
        h8_t a0 = gA0[kf], a1 = gA0[kf + 1];
        h8_t b0 = gB0[kf], b1 = gB0[kf + 1];
        *(h8_t*)&Al[r * LDT + hf * 16]     = a0;
        *(h8_t*)&Al[r * LDT + hf * 16 + 8] = a1;
        *(h8_t*)&Bl[r * LDT + hf * 16]     = b0;
        *(h8_t*)&Bl[r * LDT + hf * 16 + 8] = b1;
        __syncthreads();
        h8_t af[4], bf[4];
        #pragma unroll
        for (int i = 0; i < 4; ++i) af[i] = *(const h8_t*)&Al[(wm + i * 16 + l15) * LDT + l4 * 8];
        #pragma unroll
        for (int j = 0; j < 4; ++j) bf[j] = *(const h8_t*)&Bl[(wn + j * 16 + l15) * LDT + l4 * 8];
        #pragma unroll
        for (int i = 0; i < 4; ++i)
            #pragma unroll
            for (int j = 0; j < 4; ++j)
                acc[i][j] = __builtin_amdgcn_mfma_f32_16x16x32_f16(af[i], bf[j], acc[i][j], 0, 0, 0);
    }

    const int ns2 = N - nsplit;
    #pragma unroll
    for (int i = 0; i < 4; ++i) {
        int m0 = bm + wm + i * 16 + l4 * 4;
        #pragma unroll
        for (int j = 0; j < 4; ++j) {
            int n0 = bn + wn + j * 16 + l15;
            float bb = bias ? bias[n0] : 0.f;
            #pragma unroll
            for (int rr = 0; rr < 4; ++rr) {
                float v = acc[i][j][rr] + bb;
                if (Cf) {
                    if (n0 < nsplit) Cf[(size_t)(m0 + rr) * nsplit + n0] = v;
                    else             Cf2[(size_t)(m0 + rr) * ns2 + (n0 - nsplit)] = v;
                }
                if (Ch) Ch[(size_t)(m0 + rr) * N + n0] = (_Float16)v;
            }
        }
    }
}

// ---------------- persistent-weight RNN, int8 via MFMA ----------------
// r22 counters: active-CU VALUBusy ~70%, MfmaUtil 0% -> VALU sdot4 issue is the
// wall, matrix pipe idle.  Move the dots there: v_mfma_i32_16x16x64_i8 with h
// broadcast into all 16 B columns (1/16 tile efficiency >> sdot4 rate).
// Per wave: 4 row-tiles x 8 K-tiles = 32 MFMA/step, i32-exact accumulate.
// A-frags (weights): 20 chunks resident in VGPRs + 12 in per-lane LDS (98 KB).
// B-frags: 1 b128 LDS read per K-tile, 4 bank-disjoint addrs (free broadcast).
// Epilogue: diagonal lanes (l&15==0, col 0) write C rows (l>>4)*4+reg as b128
// into ipart; thread tid finalizes row tid.  2 barriers/step.
__global__ __launch_bounds__(512) void k_rnn(
    const uint4* __restrict__ W5,         // [32][512] A-fragment chunks
    const float* __restrict__ fac,        // [512] weight dequant scale (max/127)
    const _Float16* __restrict__ pre,     // [B,T,H] f16 pre-activation
    _Float16* __restrict__ out) {         // [B,T,H] f16 hidden states
    __shared__ __align__(16) uint4 WL[12 * 512];          // 96 KiB A-frag LDS share
    __shared__ __align__(16) signed char h_q[2][H_];      // 1 KiB h double buffer
    __shared__ __align__(16) int ipart[H_];               // 2 KiB step results

    const int tid = threadIdx.x;
    const int b = blockIdx.x;
    const int g16 = ((tid >> 4) & 3) * 16;   // lane k-group byte offset

    // resident A-frag claims: slots 0..19 (K-tiles 0..4)
    uint4 wa[20];
    #pragma unroll
    for (int s = 0; s < 20; ++s) wa[s] = W5[s * 512 + tid];
    #pragma unroll
    for (int s = 0; s < 12; ++s) WL[s * 512 + tid] = W5[(20 + s) * 512 + tid];
    if (tid < 32) ((uint4*)&h_q[0][0])[tid] = make_uint4(0u, 0u, 0u, 0u);
    __syncthreads();

    // this thread finalizes row `tid`
    const size_t base = (size_t)b * T_ * H_ + tid;
    float pcur = (float)pre[base];
    const float facr = fac[tid] * (1.f / 127.f);
    const bool diag = (tid & 15) == 0;
    const int wrow = (tid >> 6) * 64 + ((tid >> 4) & 3) * 4;  // epilogue row base

    for (int t = 0; t < T_; ++t) {
        int tn = (t + 1 < T_) ? t + 1 : t;
        _Float16 pnx = pre[base + (size_t)tn * H_];

        v4i a0 = {0, 0, 0, 0}, a1 = {0, 0, 0, 0}, a2 = {0, 0, 0, 0}, a3 = {0, 0, 0, 0};
        const signed char* hb = &h_q[t & 1][0];
        #pragma unroll
        for (int kt = 0; kt < 5; ++kt) {
            v4i bf = *(const v4i*)(hb + kt * 64 + g16);
            a0 = __builtin_amdgcn_mfma_i32_16x16x64_i8(
                     __builtin_bit_cast(v4i, wa[kt * 4 + 0]), bf, a0, 0, 0, 0);
            a1 = __builtin_amdgcn_mfma_i32_16x16x64_i8(
                     __builtin_bit_cast(v4i, wa[kt * 4 + 1]), bf, a1, 0, 0, 0);
            a2 = __builtin_amdgcn_mfma_i32_16x16x64_i8(
                     __builtin_bit_cast(v4i, wa[kt * 4 + 2]), bf, a2, 0, 0, 0);
            a3 = __builtin_amdgcn_mfma_i32_16x16x64_i8(
                     __builtin_bit_cast(v4i, wa[kt * 4 + 3]), bf, a3, 0, 0, 0);
        }
        #pragma unroll
        for (int kt = 5; kt < 8; ++kt) {
            v4i bf = *(const v4i*)(hb + kt * 64 + g16);
            int s0 = (kt - 5) * 4;
            a0 = __builtin_amdgcn_mfma_i32_16x16x64_i8(
                     __builtin_bit_cast(v4i, WL[(s0 + 0) * 512 + tid]), bf, a0, 0, 0, 0);
            a1 = __builtin_amdgcn_mfma_i32_16x16x64_i8(
                     __builtin_bit_cast(v4i, WL[(s0 + 1) * 512 + tid]), bf, a1, 0, 0, 0);
            a2 = __builtin_amdgcn_mfma_i32_16x16x64_i8(
                     __builtin_bit_cast(v4i, WL[(s0 + 2) * 512 + tid]), bf, a2, 0, 0, 0);
            a3 = __builtin_amdgcn_mfma_i32_16x16x64_i8(
                     __builtin_bit_cast(v4i, WL[(s0 + 3) * 512 + tid]), bf, a3, 0, 0, 0);
        }

        // C/D: col = lane&15, row = (lane>>4)*4 + reg (shape-determined).
        // Diagonal lanes (col 0) publish rows; all 512 rows covered exactly once.
        if (diag) {
            *(v4i*)&ipart[wrow]      = a0;   // row-tile 0: rows wrow+0..3
            *(v4i*)&ipart[wrow + 16] = a1;   // row-tile 1
            *(v4i*)&ipart[wrow + 32] = a2;   // row-tile 2
            *(v4i*)&ipart[wrow + 48] = a3;   // row-tile 3
        }
        __syncthreads();

        float hn = tanh_fast((float)ipart[tid] * facr + pcur);
        out[base + (size_t)t * H_] = (_Float16)hn;
        h_q[(t + 1) & 1][tid] = (signed char)(int)rintf(hn * 127.f);
        __syncthreads();
        pcur = (float)pnx;
    }
}

// ---------------- reparameterize: z = eps * exp(lv/2) + mu ----------------
__global__ void k_z(const float* __restrict__ mu, const float* __restrict__ lv,
                    const float* __restrict__ eps, _Float16* __restrict__ z, int n4) {
    int i = blockIdx.x * blockDim.x + threadIdx.x;
    if (i >= n4) return;
    f4_t m = ((const f4_t*)mu)[i];
    f4_t l = ((const f4_t*)lv)[i];
    f4_t e = ((const f4_t*)eps)[i];
    h4_t r;
    #pragma unroll
    for (int j = 0; j < 4; ++j) r[j] = (_Float16)(e[j] * expf(l[j] * 0.5f) + m[j]);
    ((h4_t*)z)[i] = r;
}

// ---------------- launch ----------------
extern "C" void kernel_launch(void* const* d_in, const int* in_sizes, int n_in,
                              void* d_out, int out_size, void* d_ws, size_t ws_size,
                              hipStream_t stream) {
    const float* x      = (const float*)d_in[0];
    const float* eps    = (const float*)d_in[1];
    const float* Wih_en = (const float*)d_in[2];
    const float* Whh_en = (const float*)d_in[3];
    const float* bih_en = (const float*)d_in[4];
    const float* bhh_en = (const float*)d_in[5];
    const float* W_mu   = (const float*)d_in[6];
    const float* b_mu   = (const float*)d_in[7];
    const float* W_lv   = (const float*)d_in[8];
    const float* b_lv   = (const float*)d_in[9];
    const float* Wih_de = (const float*)d_in[10];
    const float* Whh_de = (const float*)d_in[11];
    const float* bih_de = (const float*)d_in[12];
    const float* bhh_de = (const float*)d_in[13];
    const float* W_mux  = (const float*)d_in[14];
    const float* b_mux  = (const float*)d_in[15];
    const float* W_lvx  = (const float*)d_in[16];
    const float* b_lvx  = (const float*)d_in[17];
    float* out = (float*)d_out;

    char* ws = (char*)d_ws;
    _Float16* Wih_en_h = (_Float16*)(ws + 0);        // 512*128 f16
    _Float16* W_mu_h   = (_Float16*)(ws + 655360);   // [512][512], contiguous with
    _Float16* W_lv_h   = (_Float16*)(ws + 1179648);  // W_lv -> stacked [1024][512]
    _Float16* Wz_h     = (_Float16*)(ws + 1703936);
    _Float16* Wmux_h   = (_Float16*)(ws + 2752512);  // [128][512], contiguous with
    _Float16* Wlvx_h   = (_Float16*)(ws + 2883584);  // Wlvx -> stacked [256][512]
    float*    benc     = (float*)(ws + 3014656);     // 512 f32
    float*    bdec     = (float*)(ws + 3016704);
    signed char* Wq_en = (signed char*)(ws + 3018752);  // 512*512 i8 (row-major)
    signed char* Wq_de = (signed char*)(ws + 3280896);  // 512*512 i8
    float*    fac_en   = (float*)(ws + 3543040);     // 512 f32
    float*    fac_de   = (float*)(ws + 3545088);
    float*    bmulv    = (float*)(ws + 3547136);     // 1024 f32 stacked bias
    float*    bmuxlvx  = (float*)(ws + 3551232);     // 256 f32 stacked bias
    uint4*    W5_en    = (uint4*)(ws + 3552256);     // [32][512] A-frag chunks (256 KB)
    uint4*    W5_de    = (uint4*)(ws + 3814400);     // 256 KB
    _Float16* x_h      = (_Float16*)(ws + 4194304);  // 64*512*128
    _Float16* pre_h    = (_Float16*)(ws + 12582912); // 64*512*512  (pre_en, then pre_de)
    _Float16* act_h    = (_Float16*)(ws + 46137344); // 64*512*512  (y, then decoder outputs)
    _Float16* z_h      = (_Float16*)(ws + 79691776); // 64*512*512

    const int thr = 256;
    k_cast_f16<<<(65536 + thr - 1) / thr, thr, 0, stream>>>(Wih_en, Wih_en_h, 65536);
    k_cast_f16<<<(262144 + thr - 1) / thr, thr, 0, stream>>>(W_mu, W_mu_h, 262144);
    k_cast_f16<<<(262144 + thr - 1) / thr, thr, 0, stream>>>(W_lv, W_lv_h, 262144);
    k_cast_f16<<<(65536 + thr - 1) / thr, thr, 0, stream>>>(W_mux, Wmux_h, 65536);
    k_cast_f16<<<(65536 + thr - 1) / thr, thr, 0, stream>>>(W_lvx, Wlvx_h, 65536);
    k_cast_f16<<<(4194304 + thr - 1) / thr, thr, 0, stream>>>(x, x_h, 4194304);
    k_prep_z<<<262144 / thr, thr, 0, stream>>>(Wih_de, Wz_h);
    k_prep_bias<<<1, 512, 0, stream>>>(bih_en, bhh_en, benc);
    k_prep_bias<<<1, 512, 0, stream>>>(bih_de, bhh_de, bdec);
    k_cat2<<<4, 256, 0, stream>>>(b_mu, b_lv, bmulv, 512);
    k_cat2<<<1, 256, 0, stream>>>(b_mux, b_lvx, bmuxlvx, 128);
    // int8 quantization of recurrent weights (per-row scales) + A-frag repack
    k_quant<<<512, 128, 0, stream>>>(Whh_en, 512, nullptr, 0, Wq_en, fac_en);
    k_quant<<<512, 128, 0, stream>>>(Wih_de, 1024, Whh_de, 512, Wq_de, fac_de);
    k_repack<<<64, 256, 0, stream>>>(Wq_en, W5_en);
    k_repack<<<64, 256, 0, stream>>>(Wq_de, W5_de);

    dim3 gFull(32768 / BM, 512 / BN);    // 256 x 4
    dim3 gWide(32768 / BM, 1024 / BN);   // 256 x 8 (fused mu|lv)
    dim3 gNarrow(32768 / BM, 256 / BN);  // 256 x 2 (fused mux|lvx)

    // encoder pre-activation: x @ Wih_en^T + (bih_en + bhh_en)
    k_gemm<<<gFull, 256, 0, stream>>>(x_h, Wih_en_h, benc, nullptr, nullptr, pre_h,
                                      32768, 512, 512, 128);
    // encoder recurrence -> y
    k_rnn<<<64, 512, 0, stream>>>(W5_en, fac_en, pre_h, act_h);
    // fused mu_post | logsigma2_post (stacked weights, split epilogue)
    k_gemm<<<gWide, 256, 0, stream>>>(act_h, W_mu_h, bmulv, out, out + 16777216, nullptr,
                                      32768, 1024, 512, 512);
    // z = eps * exp(lv/2) + mu
    k_z<<<4194304 / thr, thr, 0, stream>>>(out, out + 16777216, eps, z_h, 4194304);
    // decoder pre-activation: z @ Wz^T + (bih_de + bhh_de)
    k_gemm<<<gFull, 256, 0, stream>>>(z_h, Wz_h, bdec, nullptr, nullptr, pre_h,
                                      32768, 512, 512, 512);
    // decoder recurrence -> outputs (reuse act_h; y is dead)
    k_rnn<<<64, 512, 0, stream>>>(W5_de, fac_de, pre_h, act_h);
    // fused mu_xhat | logsigma2_xhat
    k_gemm<<<gNarrow, 256, 0, stream>>>(act_h, Wmux_h, bmuxlvx, out + 33554432, out + 37748736,
                                        nullptr, 32768, 256, 128, 512);
}

// Round 24
// 1018.872 us; speedup vs baseline: 1.2395x; 1.2395x over previous
//
#include <hip/hip_runtime.h>

typedef _Float16 h2_t __attribute__((ext_vector_type(2)));
typedef _Float16 h4_t __attribute__((ext_vector_type(4)));
typedef _Float16 h8_t __attribute__((ext_vector_type(8)));
typedef float    f4_t __attribute__((ext_vector_type(4)));

#define B_  64
#define T_  512
#define F_  128
#define H_  512

// int8 dot helpers
static __device__ __forceinline__ int d4(int acc, unsigned a, unsigned b) {
#if __has_builtin(__builtin_amdgcn_sdot4)
    return __builtin_amdgcn_sdot4((int)a, (int)b, acc, false);
#else
    #pragma unroll
    for (int i = 0; i < 4; ++i)
        acc += (int)(signed char)((a >> (8 * i)) & 0xff) *
               (int)(signed char)((b >> (8 * i)) & 0xff);
    return acc;
#endif
}
static __device__ __forceinline__ int dot16i8(int acc, uint4 w, uint4 h) {
    acc = d4(acc, w.x, h.x);
    acc = d4(acc, w.y, h.y);
    acc = d4(acc, w.z, h.z);
    acc = d4(acc, w.w, h.w);
    return acc;
}

// xor-1 partner fetch within a DPP quad (pure VALU)
static __device__ __forceinline__ int dpp_xor1(int x) {
#if __has_builtin(__builtin_amdgcn_mov_dpp)
    return __builtin_amdgcn_mov_dpp(x, 0xB1, 0xF, 0xF, true);  // quad_perm [1,0,3,2]
#else
    return __shfl_xor(x, 1);
#endif
}

// fast tanh: sign(x) * (1 - e) / (1 + e), e = exp(-2|x|).  ~8 VALU ops
// (v_exp_f32 + v_rcp_f32) vs library tanhf's ~30-50.  |err| < 2e-6, far below
// the int8 quantization noise (~1e-3).
static __device__ __forceinline__ float tanh_fast(float x) {
    float ax = fabsf(x);
    float e = __expf(-2.f * ax);
    float r = (1.f - e) * __frcp_rn(1.f + e);
    return copysignf(r, x);
}

// ---------------- prep kernels ----------------
__global__ void k_cast_f16(const float* __restrict__ src, _Float16* __restrict__ dst, int n) {
    int i = blockIdx.x * blockDim.x + threadIdx.x;
    if (i < n) dst[i] = (_Float16)src[i];
}

// Wz[c][k] = Wih_de[c][512+k]  (z-contribution of the decoder input weight)
__global__ void k_prep_z(const float* __restrict__ Wih_de, _Float16* __restrict__ Wz) {
    int i = blockIdx.x * blockDim.x + threadIdx.x;   // over 512*512
    int cc = i >> 9, kk = i & 511;
    Wz[i] = (_Float16)Wih_de[cc * 1024 + 512 + kk];
}

__global__ void k_prep_bias(const float* __restrict__ a, const float* __restrict__ b,
                            float* __restrict__ o) {
    int i = threadIdx.x;
    o[i] = a[i] + b[i];
}

// o[0..n) = a, o[n..2n) = b
__global__ void k_cat2(const float* __restrict__ a, const float* __restrict__ b,
                       float* __restrict__ o, int n) {
    int i = blockIdx.x * blockDim.x + threadIdx.x;
    if (i < 2 * n) o[i] = (i < n) ? a[i] : b[i - n];
}

// per-row symmetric int8 quantization of W (optionally A+B elementwise).
__global__ void k_quant(const float* __restrict__ A, int sA,
                        const float* __restrict__ Bo, int sB,
                        signed char* __restrict__ q, float* __restrict__ fac) {
    __shared__ float red[128];
    const int c = blockIdx.x, t = threadIdx.x;
    f4_t v = *(const f4_t*)(A + (size_t)c * sA + t * 4);
    if (Bo) {
        f4_t vb = *(const f4_t*)(Bo + (size_t)c * sB + t * 4);
        v = v + vb;
    }
    float m = fmaxf(fmaxf(fabsf(v[0]), fabsf(v[1])), fmaxf(fabsf(v[2]), fabsf(v[3])));
    red[t] = m;
    __syncthreads();
    for (int o = 64; o; o >>= 1) {
        if (t < o) red[t] = fmaxf(red[t], red[t + o]);
        __syncthreads();
    }
    float mx = red[0];
    float inv = mx > 0.f ? 127.f / mx : 0.f;
    unsigned r = 0;
    #pragma unroll
    for (int i = 0; i < 4; ++i) {
        int qi = (int)rintf(fminf(fmaxf(v[i] * inv, -127.f), 127.f));
        r |= ((unsigned)(unsigned char)(signed char)qi) << (8 * i);
    }
    *(unsigned*)(q + (size_t)c * 512 + t * 4) = r;
    if (t == 0) fac[c] = mx > 0.f ? mx / 127.f : 0.f;
}

// repack Wq [512][512] i8 into chunk-major W2: W2[j*512 + tid] = 16-byte chunk j
// of k_rnn thread tid (j<16: row tid&~1; j>=16: row tid|1; K-half = tid&1).
// Makes EVERY weight access in k_rnn (initial load and compiler restream)
// coalesced: 64 consecutive lanes read 64 consecutive uint4s.
__global__ void k_repack(const signed char* __restrict__ Wq, uint4* __restrict__ W2) {
    int gid = blockIdx.x * blockDim.x + threadIdx.x;   // over 32*512
    int j = gid >> 9, tid2 = gid & 511;
    int half = tid2 & 1;
    int row = (j < 16) ? (tid2 & ~1) : (tid2 | 1);
    int cj = j & 15;
    W2[gid] = *(const uint4*)(Wq + (size_t)row * 512 + half * 256 + cj * 16);
}

// ---------------- GEMM: C[M,N] = A[M,K] @ Bt[N,K]^T + bias[N] ----------------
// Split epilogue: cols [0,nsplit) -> Cf (row stride nsplit), cols [nsplit,N)
// -> Cf2 (row stride N-nsplit). For unsplit calls pass nsplit=N, Cf2=nullptr.
#define BM 128
#define BN 128
#define BK 32
#define LDT 40   // padded LDS row stride in f16 units

__global__ __launch_bounds__(256) void k_gemm(
    const _Float16* __restrict__ A, const _Float16* __restrict__ Bt,
    const float* __restrict__ bias,
    float* __restrict__ Cf, float* __restrict__ Cf2, _Float16* __restrict__ Ch,
    int M, int N, int nsplit, int K) {
    __shared__ _Float16 Al[BM * LDT];
    __shared__ _Float16 Bl[BN * LDT];
    const int tid = threadIdx.x;
    const int bm = blockIdx.x * BM, bn = blockIdx.y * BN;
    const int wid = tid >> 6, lane = tid & 63;
    const int wm = (wid >> 1) * 64, wn = (wid & 1) * 64;
    const int l15 = lane & 15, l4 = lane >> 4;

    f4_t acc[4][4];
    #pragma unroll
    for (int i = 0; i < 4; ++i)
        #pragma unroll
        for (int j = 0; j < 4; ++j) {
            f4_t zz = {0.f, 0.f, 0.f, 0.f};
            acc[i][j] = zz;
        }

    const int r = tid >> 1, hf = tid & 1;
    const h8_t* gA0 = (const h8_t*)(A + (size_t)(bm + r) * K);
    const h8_t* gB0 = (const h8_t*)(Bt + (size_t)(bn + r) * K);

    for (int k0 = 0; k0 < K; k0 += BK) {
        __syncthreads();
        int kf = (k0 >> 3) + hf * 2;
        h8_t a0 = gA0[kf], a1 = gA0[kf + 1];
        h8_t b0 = gB0[kf], b1 = gB0[kf + 1];
        *(h8_t*)&Al[r * LDT + hf * 16]     = a0;
        *(h8_t*)&Al[r * LDT + hf * 16 + 8] = a1;
        *(h8_t*)&Bl[r * LDT + hf * 16]     = b0;
        *(h8_t*)&Bl[r * LDT + hf * 16 + 8] = b1;
        __syncthreads();
        h8_t af[4], bf[4];
        #pragma unroll
        for (int i = 0; i < 4; ++i) af[i] = *(const h8_t*)&Al[(wm + i * 16 + l15) * LDT + l4 * 8];
        #pragma unroll
        for (int j = 0; j < 4; ++j) bf[j] = *(const h8_t*)&Bl[(wn + j * 16 + l15) * LDT + l4 * 8];
        #pragma unroll
        for (int i = 0; i < 4; ++i)
            #pragma unroll
            for (int j = 0; j < 4; ++j)
                acc[i][j] = __builtin_amdgcn_mfma_f32_16x16x32_f16(af[i], bf[j], acc[i][j], 0, 0, 0);
    }

    const int ns2 = N - nsplit;
    #pragma unroll
    for (int i = 0; i < 4; ++i) {
        int m0 = bm + wm + i * 16 + l4 * 4;
        #pragma unroll
        for (int j = 0; j < 4; ++j) {
            int n0 = bn + wn + j * 16 + l15;
            float bb = bias ? bias[n0] : 0.f;
            #pragma unroll
            for (int rr = 0; rr < 4; ++rr) {
                float v = acc[i][j][rr] + bb;
                if (Cf) {
                    if (n0 < nsplit) Cf[(size_t)(m0 + rr) * nsplit + n0] = v;
                    else             Cf2[(size_t)(m0 + rr) * ns2 + (n0 - nsplit)] = v;
                }
                if (Ch) Ch[(size_t)(m0 + rr) * N + n0] = (_Float16)v;
            }
        }
    }
}

// ---------------- persistent-weight RNN, int8 (r22 champion, restored) ----------------
// r16-r23 surveyed 8 structural variants (LDS-instr 9-19, 1-2 barriers,
// conflict-free/conflicted, scattered/coalesced/zero restream, VALU sdot4 vs
// MFMA): all land 406-540 us. This r22 design is the best (406 us): chunk-major
// W2 (coalesced resident loads + coalesced stream of 12 chunks), padded-half h
// double buffer (1 barrier), DPP-pair exchange, 4 accumulators (8-deep chains),
// tanh_fast. r23's MFMA variant proved the matrix pipe is latency-bound at N=1
// (MfmaUtil 10%, VALUBusy 5%): serial chain depth dominates, revert.
#define HHS 272   // padded K-half stride in bytes (256 + 16)
__global__ __launch_bounds__(512) void k_rnn(
    const uint4* __restrict__ W2,         // [32][512] chunk-major weight chunks
    const float* __restrict__ fac,        // [512] weight dequant scale (max/127)
    const _Float16* __restrict__ pre,     // [B,T,H] f16 pre-activation
    _Float16* __restrict__ out) {         // [B,T,H] f16 hidden states
    __shared__ __align__(16) signed char h_q[2][2 * HHS]; // 1088 B double buffer

    const int tid = threadIdx.x;
    const int half = tid & 1;        // K-half owned by this lane
    const int b = blockIdx.x;

    // resident claims: chunks 0..9 of both rows (coalesced loads)
    uint4 wa[10], wb[10];
    #pragma unroll
    for (int j = 0; j < 10; ++j) {
        wa[j] = W2[j * 512 + tid];
        wb[j] = W2[(16 + j) * 512 + tid];
    }
    if (tid < 34) ((uint4*)&h_q[0][0])[tid] = make_uint4(0u, 0u, 0u, 0u);
    __syncthreads();

    // this thread finalizes row `tid`
    const size_t base = (size_t)b * T_ * H_ + tid;
    float pcur = (float)pre[base];
    const float facr = fac[tid] * (1.f / 127.f);
    const int woff = ((tid >> 8) * HHS) + (tid & 255);   // padded slot of row `tid`

    for (int t = 0; t < T_; ++t) {
        int tn = (t + 1 < T_) ? t + 1 : t;
        _Float16 pnx = pre[base + (size_t)tn * H_];

        // 4 accumulators: chains 8-deep (was 16) -> half the dependent latency
        int i0a = 0, i0b = 0, i1a = 0, i1b = 0;
        const uint4* hv = (const uint4*)&h_q[t & 1][half * HHS];
        #pragma unroll
        for (int j = 0; j < 8; ++j) {
            uint4 hh = hv[j];
            i0a = dot16i8(i0a, wa[j], hh);
            i1a = dot16i8(i1a, wb[j], hh);
        }
        #pragma unroll
        for (int j = 8; j < 10; ++j) {
            uint4 hh = hv[j];
            i0b = dot16i8(i0b, wa[j], hh);
            i1b = dot16i8(i1b, wb[j], hh);
        }
        #pragma unroll
        for (int j = 10; j < 16; ++j) {
            uint4 hh = hv[j];
            i0b = dot16i8(i0b, W2[j * 512 + tid], hh);        // coalesced L2 stream
            i1b = dot16i8(i1b, W2[(16 + j) * 512 + tid], hh);
        }
        int i0 = i0a + i0b;   // row (tid&~1), this K-half
        int i1 = i1a + i1b;   // row (tid|1),  this K-half

        // exchange: my own-row partial + partner's other-accumulator (exact int)
        int own  = half ? i1 : i0;
        int give = half ? i0 : i1;
        int tot = own + dpp_xor1(give);

        float hn = tanh_fast((float)tot * facr + pcur);
        out[base + (size_t)t * H_] = (_Float16)hn;
        h_q[(t + 1) & 1][woff] = (signed char)(int)rintf(hn * 127.f);
        __syncthreads();
        pcur = (float)pnx;
    }
}

// ---------------- reparameterize: z = eps * exp(lv/2) + mu ----------------
__global__ void k_z(const float* __restrict__ mu, const float* __restrict__ lv,
                    const float* __restrict__ eps, _Float16* __restrict__ z, int n4) {
    int i = blockIdx.x * blockDim.x + threadIdx.x;
    if (i >= n4) return;
    f4_t m = ((const f4_t*)mu)[i];
    f4_t l = ((const f4_t*)lv)[i];
    f4_t e = ((const f4_t*)eps)[i];
    h4_t r;
    #pragma unroll
    for (int j = 0; j < 4; ++j) r[j] = (_Float16)(e[j] * expf(l[j] * 0.5f) + m[j]);
    ((h4_t*)z)[i] = r;
}

// ---------------- launch ----------------
extern "C" void kernel_launch(void* const* d_in, const int* in_sizes, int n_in,
                              void* d_out, int out_size, void* d_ws, size_t ws_size,
                              hipStream_t stream) {
    const float* x      = (const float*)d_in[0];
    const float* eps    = (const float*)d_in[1];
    const float* Wih_en = (const float*)d_in[2];
    const float* Whh_en = (const float*)d_in[3];
    const float* bih_en = (const float*)d_in[4];
    const float* bhh_en = (const float*)d_in[5];
    const float* W_mu   = (const float*)d_in[6];
    const float* b_mu   = (const float*)d_in[7];
    const float* W_lv   = (const float*)d_in[8];
    const float* b_lv   = (const float*)d_in[9];
    const float* Wih_de = (const float*)d_in[10];
    const float* Whh_de = (const float*)d_in[11];
    const float* bih_de = (const float*)d_in[12];
    const float* bhh_de = (const float*)d_in[13];
    const float* W_mux  = (const float*)d_in[14];
    const float* b_mux  = (const float*)d_in[15];
    const float* W_lvx  = (const float*)d_in[16];
    const float* b_lvx  = (const float*)d_in[17];
    float* out = (float*)d_out;

    char* ws = (char*)d_ws;
    _Float16* Wih_en_h = (_Float16*)(ws + 0);        // 512*128 f16
    _Float16* W_mu_h   = (_Float16*)(ws + 655360);   // [512][512], contiguous with
    _Float16* W_lv_h   = (_Float16*)(ws + 1179648);  // W_lv -> stacked [1024][512]
    _Float16* Wz_h     = (_Float16*)(ws + 1703936);
    _Float16* Wmux_h   = (_Float16*)(ws + 2752512);  // [128][512], contiguous with
    _Float16* Wlvx_h   = (_Float16*)(ws + 2883584);  // Wlvx -> stacked [256][512]
    float*    benc     = (float*)(ws + 3014656);     // 512 f32
    float*    bdec     = (float*)(ws + 3016704);
    signed char* Wq_en = (signed char*)(ws + 3018752);  // 512*512 i8 (row-major)
    signed char* Wq_de = (signed char*)(ws + 3280896);  // 512*512 i8
    float*    fac_en   = (float*)(ws + 3543040);     // 512 f32
    float*    fac_de   = (float*)(ws + 3545088);
    float*    bmulv    = (float*)(ws + 3547136);     // 1024 f32 stacked bias
    float*    bmuxlvx  = (float*)(ws + 3551232);     // 256 f32 stacked bias
    uint4*    W2_en    = (uint4*)(ws + 3552256);     // [32][512] chunk-major (256 KB)
    uint4*    W2_de    = (uint4*)(ws + 3814400);     // 256 KB
    _Float16* x_h      = (_Float16*)(ws + 4194304);  // 64*512*128
    _Float16* pre_h    = (_Float16*)(ws + 12582912); // 64*512*512  (pre_en, then pre_de)
    _Float16* act_h    = (_Float16*)(ws + 46137344); // 64*512*512  (y, then decoder outputs)
    _Float16* z_h      = (_Float16*)(ws + 79691776); // 64*512*512

    const int thr = 256;
    k_cast_f16<<<(65536 + thr - 1) / thr, thr, 0, stream>>>(Wih_en, Wih_en_h, 65536);
    k_cast_f16<<<(262144 + thr - 1) / thr, thr, 0, stream>>>(W_mu, W_mu_h, 262144);
    k_cast_f16<<<(262144 + thr - 1) / thr, thr, 0, stream>>>(W_lv, W_lv_h, 262144);
    k_cast_f16<<<(65536 + thr - 1) / thr, thr, 0, stream>>>(W_mux, Wmux_h, 65536);
    k_cast_f16<<<(65536 + thr - 1) / thr, thr, 0, stream>>>(W_lvx, Wlvx_h, 65536);
    k_cast_f16<<<(4194304 + thr - 1) / thr, thr, 0, stream>>>(x, x_h, 4194304);
    k_prep_z<<<262144 / thr, thr, 0, stream>>>(Wih_de, Wz_h);
    k_prep_bias<<<1, 512, 0, stream>>>(bih_en, bhh_en, benc);
    k_prep_bias<<<1, 512, 0, stream>>>(bih_de, bhh_de, bdec);
    k_cat2<<<4, 256, 0, stream>>>(b_mu, b_lv, bmulv, 512);
    k_cat2<<<1, 256, 0, stream>>>(b_mux, b_lvx, bmuxlvx, 128);
    // int8 quantization of recurrent weights (per-row scales) + chunk-major repack
    k_quant<<<512, 128, 0, stream>>>(Whh_en, 512, nullptr, 0, Wq_en, fac_en);
    k_quant<<<512, 128, 0, stream>>>(Wih_de, 1024, Whh_de, 512, Wq_de, fac_de);
    k_repack<<<64, 256, 0, stream>>>(Wq_en, W2_en);
    k_repack<<<64, 256, 0, stream>>>(Wq_de, W2_de);

    dim3 gFull(32768 / BM, 512 / BN);    // 256 x 4
    dim3 gWide(32768 / BM, 1024 / BN);   // 256 x 8 (fused mu|lv)
    dim3 gNarrow(32768 / BM, 256 / BN);  // 256 x 2 (fused mux|lvx)

    // encoder pre-activation: x @ Wih_en^T + (bih_en + bhh_en)
    k_gemm<<<gFull, 256, 0, stream>>>(x_h, Wih_en_h, benc, nullptr, nullptr, pre_h,
                                      32768, 512, 512, 128);
    // encoder recurrence -> y
    k_rnn<<<64, 512, 0, stream>>>(W2_en, fac_en, pre_h, act_h);
    // fused mu_post | logsigma2_post (stacked weights, split epilogue)
    k_gemm<<<gWide, 256, 0, stream>>>(act_h, W_mu_h, bmulv, out, out + 16777216, nullptr,
                                      32768, 1024, 512, 512);
    // z = eps * exp(lv/2) + mu
    k_z<<<4194304 / thr, thr, 0, stream>>>(out, out + 16777216, eps, z_h, 4194304);
    // decoder pre-activation: z @ Wz^T + (bih_de + bhh_de)
    k_gemm<<<gFull, 256, 0, stream>>>(z_h, Wz_h, bdec, nullptr, nullptr, pre_h,
                                      32768, 512, 512, 512);
    // decoder recurrence -> outputs (reuse act_h; y is dead)
    k_rnn<<<64, 512, 0, stream>>>(W2_de, fac_de, pre_h, act_h);
    // fused mu_xhat | logsigma2_xhat
    k_gemm<<<gNarrow, 256, 0, stream>>>(act_h, Wmux_h, bmuxlvx, out + 33554432, out + 37748736,
                                        nullptr, 32768, 256, 128, 512);
}